// Round 3
// baseline (591.911 us; speedup 1.0000x reference)
//
#include <hip/hip_runtime.h>

#define D 256
#define TQ 32

// ---------------- CSR-build path (no float atomics) ----------------

__global__ __launch_bounds__(256) void flag_kernel(
    const int* __restrict__ nid, unsigned char* __restrict__ flags, int Q)
{
    int q = blockIdx.x * 256 + threadIdx.x;
    if (q < Q) flags[nid[q]] = 1;
}

__global__ __launch_bounds__(256) void hist_kernel(
    const int* __restrict__ edst, const unsigned char* __restrict__ flags,
    int* __restrict__ counts, int E)
{
    int stride = gridDim.x * 256;
    for (int e = blockIdx.x * 256 + threadIdx.x; e < E; e += stride) {
        int d = edst[e];
        if (flags[d]) atomicAdd(&counts[d], 1);
    }
}

__global__ __launch_bounds__(256) void alloc_kernel(
    const int* __restrict__ counts, int* __restrict__ base,
    int* __restrict__ pos, int* __restrict__ total, int N)
{
    int n = blockIdx.x * 256 + threadIdx.x;
    if (n >= N) return;
    int c = counts[n];
    int b = 0;
    if (c > 0) b = atomicAdd(total, c);
    base[n] = b;
    pos[n]  = b;
}

__global__ __launch_bounds__(256) void bucket_kernel(
    const int* __restrict__ esrc, const int* __restrict__ edst,
    const float* __restrict__ ew, const unsigned char* __restrict__ flags,
    int* __restrict__ pos, int2* __restrict__ bucket, int E)
{
    int stride = gridDim.x * 256;
    for (int e = blockIdx.x * 256 + threadIdx.x; e < E; e += stride) {
        int d = edst[e];
        if (flags[d]) {
            int idx = atomicAdd(&pos[d], 1);
            bucket[idx] = make_int2(esrc[e], __float_as_int(ew[e]));
        }
    }
}

// One wave (64 lanes) per node: lane l owns float4 #l of the 256-float row.
__global__ __launch_bounds__(256) void accum_nodes(
    const float4* __restrict__ emb,      // [N][64] float4
    const int2*   __restrict__ bucket,   // packed {src, w}
    const int*    __restrict__ base,
    const int*    __restrict__ counts,
    const unsigned char* __restrict__ flags,
    float4*       __restrict__ agg,      // [N][64] float4
    int N)
{
    const int lane = threadIdx.x & 63;
    const int wid  = (int)((blockIdx.x * 256 + threadIdx.x) >> 6);
    if (wid >= N) return;
    if (!flags[wid]) return;

    const int b = base[wid];
    const int c = counts[wid];
    float4 acc = make_float4(0.f, 0.f, 0.f, 0.f);

    int i = 0;
    for (; i + 4 <= c; i += 4) {
        int2 s0 = bucket[b + i + 0];
        int2 s1 = bucket[b + i + 1];
        int2 s2 = bucket[b + i + 2];
        int2 s3 = bucket[b + i + 3];
        float4 v0 = emb[(size_t)s0.x * (D / 4) + lane];
        float4 v1 = emb[(size_t)s1.x * (D / 4) + lane];
        float4 v2 = emb[(size_t)s2.x * (D / 4) + lane];
        float4 v3 = emb[(size_t)s3.x * (D / 4) + lane];
        float w0 = __int_as_float(s0.y), w1 = __int_as_float(s1.y);
        float w2 = __int_as_float(s2.y), w3 = __int_as_float(s3.y);
        acc.x += v0.x * w0; acc.y += v0.y * w0; acc.z += v0.z * w0; acc.w += v0.w * w0;
        acc.x += v1.x * w1; acc.y += v1.y * w1; acc.z += v1.z * w1; acc.w += v1.w * w1;
        acc.x += v2.x * w2; acc.y += v2.y * w2; acc.z += v2.z * w2; acc.w += v2.w * w2;
        acc.x += v3.x * w3; acc.y += v3.y * w3; acc.z += v3.z * w3; acc.w += v3.w * w3;
    }
    for (; i < c; ++i) {
        int2 s = bucket[b + i];
        float4 v = emb[(size_t)s.x * (D / 4) + lane];
        float w = __int_as_float(s.y);
        acc.x += v.x * w; acc.y += v.y * w; acc.z += v.z * w; acc.w += v.w * w;
    }
    agg[(size_t)wid * (D / 4) + lane] = acc;
}

// ---------------- Fallback path (ws too small): atomics ----------------

__global__ __launch_bounds__(256) void scatter_edges(
    const float4* __restrict__ emb, const int* __restrict__ esrc,
    const int* __restrict__ edst, const float* __restrict__ ew,
    float* __restrict__ agg, int E)
{
    const int lane = threadIdx.x & 63;
    const int wid  = (int)((blockIdx.x * blockDim.x + threadIdx.x) >> 6);
    const int nw   = (int)((gridDim.x * blockDim.x) >> 6);
    for (int e = wid; e < E; e += nw) {
        const int   s = esrc[e];
        const int   d = edst[e];
        const float w = ew[e];
        float4 v = emb[(size_t)s * (D / 4) + lane];
        float* o = agg + (size_t)d * D + lane * 4;
        unsafeAtomicAdd(o + 0, v.x * w);
        unsafeAtomicAdd(o + 1, v.y * w);
        unsafeAtomicAdd(o + 2, v.z * w);
        unsafeAtomicAdd(o + 3, v.w * w);
    }
}

// ---------------- Phase 2: out[q][j] = dot(agg[node_ids[q]], W[j]) + b[j] ----------------
// Register-tiled: wave rg owns rows rg*8..rg*8+7, lane jg owns cols jg*4..jg*4+3.
// All 64 lanes of a wave read the SAME feats LDS address per step -> broadcast
// (no bank traffic); W reads are L1-resident across 4 consecutive k4 steps.
__global__ __launch_bounds__(256) void gather_gemm(
    const float* __restrict__ agg, const int* __restrict__ nid,
    const float* __restrict__ W, const float* __restrict__ b,
    float* __restrict__ out, int Q)
{
    __shared__ float4 fl[TQ][D / 4];    // 32 KB
    const int t  = threadIdx.x;
    const int q0 = blockIdx.x * TQ;

    // Stage feats tile: row r read by 64 consecutive threads -> coalesced 1 KB.
    for (int i = t; i < TQ * (D / 4); i += 256) {
        const int r = i >> 6;
        const int c = i & 63;
        const int q = q0 + r;
        float4 v = make_float4(0.f, 0.f, 0.f, 0.f);
        if (q < Q) v = ((const float4*)agg)[(size_t)nid[q] * (D / 4) + c];
        fl[r][c] = v;
    }
    __syncthreads();

    const int jg = t & 63;              // column group: cols jg*4 .. jg*4+3
    const int rg = t >> 6;              // wave id = row group: rows rg*8 .. rg*8+7

    float acc[8][4];
    #pragma unroll
    for (int r = 0; r < 8; ++r)
        #pragma unroll
        for (int c = 0; c < 4; ++c) acc[r][c] = 0.f;

    const float4* Wv = (const float4*)W;    // W[j][k] row-major, float4 over k
    const size_t j0 = (size_t)jg * 4;

    for (int k4 = 0; k4 < D / 4; ++k4) {
        const float4 w0 = Wv[(j0 + 0) * (D / 4) + k4];
        const float4 w1 = Wv[(j0 + 1) * (D / 4) + k4];
        const float4 w2 = Wv[(j0 + 2) * (D / 4) + k4];
        const float4 w3 = Wv[(j0 + 3) * (D / 4) + k4];
        #pragma unroll
        for (int r = 0; r < 8; ++r) {
            const float4 f = fl[rg * 8 + r][k4];   // wave-uniform -> LDS broadcast
            acc[r][0] += f.x * w0.x + f.y * w0.y + f.z * w0.z + f.w * w0.w;
            acc[r][1] += f.x * w1.x + f.y * w1.y + f.z * w1.z + f.w * w1.w;
            acc[r][2] += f.x * w2.x + f.y * w2.y + f.z * w2.z + f.w * w2.w;
            acc[r][3] += f.x * w3.x + f.y * w3.y + f.z * w3.z + f.w * w3.w;
        }
    }

    const float4 bias = ((const float4*)b)[jg];
    #pragma unroll
    for (int r = 0; r < 8; ++r) {
        const int q = q0 + rg * 8 + r;
        if (q < Q) {
            float4 o;
            o.x = acc[r][0] + bias.x;
            o.y = acc[r][1] + bias.y;
            o.z = acc[r][2] + bias.z;
            o.w = acc[r][3] + bias.w;
            ((float4*)out)[(size_t)q * (D / 4) + jg] = o;
        }
    }
}

extern "C" void kernel_launch(void* const* d_in, const int* in_sizes, int n_in,
                              void* d_out, int out_size, void* d_ws, size_t ws_size,
                              hipStream_t stream) {
    const float* emb  = (const float*)d_in[0];
    const int*   esrc = (const int*)d_in[1];
    const int*   edst = (const int*)d_in[2];
    const float* ew   = (const float*)d_in[3];
    const int*   nid  = (const int*)d_in[4];
    const float* W    = (const float*)d_in[5];
    const float* b    = (const float*)d_in[6];
    float*       out  = (float*)d_out;

    const int N = in_sizes[0] / D;   // 100000
    const int E = in_sizes[1];       // 1600000
    const int Q = in_sizes[4];       // 50000

    char* wsb = (char*)d_ws;

    size_t off_agg    = 0;
    size_t off_counts = off_agg    + (size_t)N * D * sizeof(float);
    size_t off_base   = off_counts + (size_t)N * sizeof(int);
    size_t off_pos    = off_base   + (size_t)N * sizeof(int);
    size_t off_total  = off_pos    + (size_t)N * sizeof(int);
    size_t off_flags  = off_total  + 256;
    size_t off_bucket = off_flags  + (((size_t)N + 255) / 256) * 256;
    size_t needed     = off_bucket + (size_t)E * sizeof(int2);

    float* agg = (float*)(wsb + off_agg);

    if (ws_size >= needed) {
        int*           counts = (int*)(wsb + off_counts);
        int*           basep  = (int*)(wsb + off_base);
        int*           pos    = (int*)(wsb + off_pos);
        int*           total  = (int*)(wsb + off_total);
        unsigned char* flags  = (unsigned char*)(wsb + off_flags);
        int2*          bucket = (int2*)(wsb + off_bucket);

        hipMemsetAsync(wsb + off_counts, 0, off_bucket - off_counts, stream);

        flag_kernel  <<<(Q + 255) / 256, 256, 0, stream>>>(nid, flags, Q);
        hist_kernel  <<<2048, 256, 0, stream>>>(edst, flags, counts, E);
        alloc_kernel <<<(N + 255) / 256, 256, 0, stream>>>(counts, basep, pos, total, N);
        bucket_kernel<<<2048, 256, 0, stream>>>(esrc, edst, ew, flags, pos, bucket, E);

        int nb_acc = (int)(((size_t)N * 64 + 255) / 256);
        accum_nodes<<<nb_acc, 256, 0, stream>>>((const float4*)emb, bucket, basep,
                                                counts, flags, (float4*)agg, N);
    } else {
        hipMemsetAsync(agg, 0, (size_t)N * D * sizeof(float), stream);
        scatter_edges<<<2048, 256, 0, stream>>>((const float4*)emb, esrc, edst, ew, agg, E);
    }

    const int nb = (Q + TQ - 1) / TQ;
    gather_gemm<<<nb, 256, 0, stream>>>(agg, nid, W, b, out, Q);
}

// Round 4
// 455.128 us; speedup vs baseline: 1.3005x; 1.3005x over previous
//
#include <hip/hip_runtime.h>

#define D 256
#define TQ 32

// ---------------- CSR-build path (no float atomics) ----------------

__global__ __launch_bounds__(256) void flag_kernel(
    const int* __restrict__ nid, unsigned char* __restrict__ flags, int Q)
{
    int q = blockIdx.x * 256 + threadIdx.x;
    if (q < Q) flags[nid[q]] = 1;
}

__global__ __launch_bounds__(256) void hist_kernel(
    const int* __restrict__ edst, const unsigned char* __restrict__ flags,
    int* __restrict__ counts, int E)
{
    int stride = gridDim.x * 256;
    for (int e = blockIdx.x * 256 + threadIdx.x; e < E; e += stride) {
        int d = edst[e];
        if (flags[d]) atomicAdd(&counts[d], 1);
    }
}

__global__ __launch_bounds__(256) void alloc_kernel(
    const int* __restrict__ counts, int* __restrict__ base,
    int* __restrict__ pos, int* __restrict__ total, int N)
{
    int n = blockIdx.x * 256 + threadIdx.x;
    if (n >= N) return;
    int c = counts[n];
    int b = 0;
    if (c > 0) b = atomicAdd(total, c);
    base[n] = b;
    pos[n]  = b;
}

__global__ __launch_bounds__(256) void bucket_kernel(
    const int* __restrict__ esrc, const int* __restrict__ edst,
    const float* __restrict__ ew, const unsigned char* __restrict__ flags,
    int* __restrict__ pos, int2* __restrict__ bucket, int E)
{
    int stride = gridDim.x * 256;
    for (int e = blockIdx.x * 256 + threadIdx.x; e < E; e += stride) {
        int d = edst[e];
        if (flags[d]) {
            int idx = atomicAdd(&pos[d], 1);
            bucket[idx] = make_int2(esrc[e], __float_as_int(ew[e]));
        }
    }
}

// One wave (64 lanes) per node: lane l owns float4 #l of the 256-float row.
__global__ __launch_bounds__(256) void accum_nodes(
    const float4* __restrict__ emb,      // [N][64] float4
    const int2*   __restrict__ bucket,   // packed {src, w}
    const int*    __restrict__ base,
    const int*    __restrict__ counts,
    const unsigned char* __restrict__ flags,
    float4*       __restrict__ agg,      // [N][64] float4
    int N)
{
    const int lane = threadIdx.x & 63;
    const int wid  = (int)((blockIdx.x * 256 + threadIdx.x) >> 6);
    if (wid >= N) return;
    if (!flags[wid]) return;

    const int b = base[wid];
    const int c = counts[wid];
    float4 acc = make_float4(0.f, 0.f, 0.f, 0.f);

    int i = 0;
    for (; i + 4 <= c; i += 4) {
        int2 s0 = bucket[b + i + 0];
        int2 s1 = bucket[b + i + 1];
        int2 s2 = bucket[b + i + 2];
        int2 s3 = bucket[b + i + 3];
        float4 v0 = emb[(size_t)s0.x * (D / 4) + lane];
        float4 v1 = emb[(size_t)s1.x * (D / 4) + lane];
        float4 v2 = emb[(size_t)s2.x * (D / 4) + lane];
        float4 v3 = emb[(size_t)s3.x * (D / 4) + lane];
        float w0 = __int_as_float(s0.y), w1 = __int_as_float(s1.y);
        float w2 = __int_as_float(s2.y), w3 = __int_as_float(s3.y);
        acc.x += v0.x * w0; acc.y += v0.y * w0; acc.z += v0.z * w0; acc.w += v0.w * w0;
        acc.x += v1.x * w1; acc.y += v1.y * w1; acc.z += v1.z * w1; acc.w += v1.w * w1;
        acc.x += v2.x * w2; acc.y += v2.y * w2; acc.z += v2.z * w2; acc.w += v2.w * w2;
        acc.x += v3.x * w3; acc.y += v3.y * w3; acc.z += v3.z * w3; acc.w += v3.w * w3;
    }
    for (; i < c; ++i) {
        int2 s = bucket[b + i];
        float4 v = emb[(size_t)s.x * (D / 4) + lane];
        float w = __int_as_float(s.y);
        acc.x += v.x * w; acc.y += v.y * w; acc.z += v.z * w; acc.w += v.w * w;
    }
    agg[(size_t)wid * (D / 4) + lane] = acc;
}

// ---------------- Fallback path (ws too small): atomics ----------------

__global__ __launch_bounds__(256) void scatter_edges(
    const float4* __restrict__ emb, const int* __restrict__ esrc,
    const int* __restrict__ edst, const float* __restrict__ ew,
    float* __restrict__ agg, int E)
{
    const int lane = threadIdx.x & 63;
    const int wid  = (int)((blockIdx.x * blockDim.x + threadIdx.x) >> 6);
    const int nw   = (int)((gridDim.x * blockDim.x) >> 6);
    for (int e = wid; e < E; e += nw) {
        const int   s = esrc[e];
        const int   d = edst[e];
        const float w = ew[e];
        float4 v = emb[(size_t)s * (D / 4) + lane];
        float* o = agg + (size_t)d * D + lane * 4;
        unsafeAtomicAdd(o + 0, v.x * w);
        unsafeAtomicAdd(o + 1, v.y * w);
        unsafeAtomicAdd(o + 2, v.z * w);
        unsafeAtomicAdd(o + 3, v.w * w);
    }
}

// ---------------- W transpose: Wt[k][j] = W[j][k] ----------------
__global__ __launch_bounds__(256) void transpose_w(
    const float* __restrict__ W, float* __restrict__ Wt)
{
    __shared__ float tile[16][17];
    const int bx = blockIdx.x & 15;        // 16-col tile index (k of W)
    const int by = blockIdx.x >> 4;        // 16-row tile index (j of W)
    const int tx = threadIdx.x & 15;
    const int ty = threadIdx.x >> 4;
    tile[ty][tx] = W[(size_t)(by * 16 + ty) * D + bx * 16 + tx];
    __syncthreads();
    // Wt[k][j]: k = bx*16+ty, j = by*16+tx  ->  W[j][k] = tile[tx][ty]
    Wt[(size_t)(bx * 16 + ty) * D + by * 16 + tx] = tile[tx][ty];
}

// ---------------- Phase 2: out[q][j] = dot(feats[q], W[j]) + b[j] ----------------
// Register tile: thread (rg = t>>5, cg = t&31) owns rows rg*4..+3, cols cg*8..+7.
// feats from LDS broadcast (wave-uniform addr); Wt reads coalesced (lanes cover
// a contiguous 1 KB row segment of Wt); 128 FMA per k4-step dominates.
__global__ __launch_bounds__(256) void gather_gemm(
    const float* __restrict__ agg, const int* __restrict__ nid,
    const float* __restrict__ Wt,     // [K][J] transposed weight
    const float* __restrict__ b,
    float* __restrict__ out, int Q)
{
    __shared__ float4 fl[TQ][D / 4];    // 32 KB
    const int t  = threadIdx.x;
    const int q0 = blockIdx.x * TQ;

    for (int i = t; i < TQ * (D / 4); i += 256) {
        const int r = i >> 6;
        const int c = i & 63;
        const int q = q0 + r;
        float4 v = make_float4(0.f, 0.f, 0.f, 0.f);
        if (q < Q) v = ((const float4*)agg)[(size_t)nid[q] * (D / 4) + c];
        fl[r][c] = v;
    }
    __syncthreads();

    const int cg = t & 31;              // cols cg*8 .. cg*8+7
    const int rg = t >> 5;              // rows rg*4 .. rg*4+3

    float acc[4][8];
    #pragma unroll
    for (int r = 0; r < 4; ++r)
        #pragma unroll
        for (int c = 0; c < 8; ++c) acc[r][c] = 0.f;

    const float4* Wt4 = (const float4*)Wt;   // [256][64]

    for (int k4 = 0; k4 < D / 4; ++k4) {
        const float4 f0 = fl[rg * 4 + 0][k4];
        const float4 f1 = fl[rg * 4 + 1][k4];
        const float4 f2 = fl[rg * 4 + 2][k4];
        const float4 f3 = fl[rg * 4 + 3][k4];
        #pragma unroll
        for (int kk = 0; kk < 4; ++kk) {
            const int k = k4 * 4 + kk;
            const float4 wa = Wt4[(size_t)k * (D / 4) + cg * 2 + 0];
            const float4 wb = Wt4[(size_t)k * (D / 4) + cg * 2 + 1];
            const float e0 = (&f0.x)[kk];
            const float e1 = (&f1.x)[kk];
            const float e2 = (&f2.x)[kk];
            const float e3 = (&f3.x)[kk];
            acc[0][0] += e0 * wa.x; acc[0][1] += e0 * wa.y; acc[0][2] += e0 * wa.z; acc[0][3] += e0 * wa.w;
            acc[0][4] += e0 * wb.x; acc[0][5] += e0 * wb.y; acc[0][6] += e0 * wb.z; acc[0][7] += e0 * wb.w;
            acc[1][0] += e1 * wa.x; acc[1][1] += e1 * wa.y; acc[1][2] += e1 * wa.z; acc[1][3] += e1 * wa.w;
            acc[1][4] += e1 * wb.x; acc[1][5] += e1 * wb.y; acc[1][6] += e1 * wb.z; acc[1][7] += e1 * wb.w;
            acc[2][0] += e2 * wa.x; acc[2][1] += e2 * wa.y; acc[2][2] += e2 * wa.z; acc[2][3] += e2 * wa.w;
            acc[2][4] += e2 * wb.x; acc[2][5] += e2 * wb.y; acc[2][6] += e2 * wb.z; acc[2][7] += e2 * wb.w;
            acc[3][0] += e3 * wa.x; acc[3][1] += e3 * wa.y; acc[3][2] += e3 * wa.z; acc[3][3] += e3 * wa.w;
            acc[3][4] += e3 * wb.x; acc[3][5] += e3 * wb.y; acc[3][6] += e3 * wb.z; acc[3][7] += e3 * wb.w;
        }
    }

    const float4 ba = ((const float4*)b)[cg * 2 + 0];
    const float4 bb = ((const float4*)b)[cg * 2 + 1];
    #pragma unroll
    for (int r = 0; r < 4; ++r) {
        const int q = q0 + rg * 4 + r;
        if (q < Q) {
            float4 oa, ob;
            oa.x = acc[r][0] + ba.x; oa.y = acc[r][1] + ba.y;
            oa.z = acc[r][2] + ba.z; oa.w = acc[r][3] + ba.w;
            ob.x = acc[r][4] + bb.x; ob.y = acc[r][5] + bb.y;
            ob.z = acc[r][6] + bb.z; ob.w = acc[r][7] + bb.w;
            ((float4*)out)[(size_t)q * (D / 4) + cg * 2 + 0] = oa;
            ((float4*)out)[(size_t)q * (D / 4) + cg * 2 + 1] = ob;
        }
    }
}

// Fallback GEMM reading W directly (round-2 structure), used only if ws
// can't hold Wt.
__global__ __launch_bounds__(256) void gather_gemm_w(
    const float* __restrict__ agg, const int* __restrict__ nid,
    const float* __restrict__ W, const float* __restrict__ b,
    float* __restrict__ out, int Q)
{
    __shared__ float fl[TQ][D];
    const int t  = threadIdx.x;
    const int q0 = blockIdx.x * TQ;

    for (int i = t; i < TQ * (D / 4); i += 256) {
        const int r = i >> 6;
        const int c = i & 63;
        const int q = q0 + r;
        float4 v = make_float4(0.f, 0.f, 0.f, 0.f);
        if (q < Q) v = ((const float4*)agg)[(size_t)nid[q] * (D / 4) + c];
        ((float4*)&fl[r][0])[c] = v;
    }
    __syncthreads();

    const int j = t;
    float acc[TQ];
    #pragma unroll
    for (int r = 0; r < TQ; ++r) acc[r] = 0.f;

    const float4* wr4 = (const float4*)(W + (size_t)j * D);
    for (int k4 = 0; k4 < D / 4; ++k4) {
        const float4 w4 = wr4[k4];
        #pragma unroll
        for (int r = 0; r < TQ; ++r) {
            const float4 f = ((const float4*)&fl[r][0])[k4];
            acc[r] += f.x * w4.x + f.y * w4.y + f.z * w4.z + f.w * w4.w;
        }
    }

    const float bias = b[j];
    #pragma unroll
    for (int r = 0; r < TQ; ++r) {
        const int q = q0 + r;
        if (q < Q) out[(size_t)q * D + j] = acc[r] + bias;
    }
}

extern "C" void kernel_launch(void* const* d_in, const int* in_sizes, int n_in,
                              void* d_out, int out_size, void* d_ws, size_t ws_size,
                              hipStream_t stream) {
    const float* emb  = (const float*)d_in[0];
    const int*   esrc = (const int*)d_in[1];
    const int*   edst = (const int*)d_in[2];
    const float* ew   = (const float*)d_in[3];
    const int*   nid  = (const int*)d_in[4];
    const float* W    = (const float*)d_in[5];
    const float* b    = (const float*)d_in[6];
    float*       out  = (float*)d_out;

    const int N = in_sizes[0] / D;   // 100000
    const int E = in_sizes[1];       // 1600000
    const int Q = in_sizes[4];       // 50000

    char* wsb = (char*)d_ws;

    size_t off_agg    = 0;
    size_t off_counts = off_agg    + (size_t)N * D * sizeof(float);
    size_t off_base   = off_counts + (size_t)N * sizeof(int);
    size_t off_pos    = off_base   + (size_t)N * sizeof(int);
    size_t off_total  = off_pos    + (size_t)N * sizeof(int);
    size_t off_flags  = off_total  + 256;
    size_t off_bucket = off_flags  + (((size_t)N + 255) / 256) * 256;
    size_t off_wt     = off_bucket + (size_t)E * sizeof(int2);
    size_t needed     = off_wt     + (size_t)D * D * sizeof(float);

    float* agg = (float*)(wsb + off_agg);
    float* Wt  = (float*)(wsb + off_wt);

    const bool big_ws = (ws_size >= needed);

    if (big_ws) {
        int*           counts = (int*)(wsb + off_counts);
        int*           basep  = (int*)(wsb + off_base);
        int*           pos    = (int*)(wsb + off_pos);
        int*           total  = (int*)(wsb + off_total);
        unsigned char* flags  = (unsigned char*)(wsb + off_flags);
        int2*          bucket = (int2*)(wsb + off_bucket);

        hipMemsetAsync(wsb + off_counts, 0, off_bucket - off_counts, stream);

        transpose_w  <<<256, 256, 0, stream>>>(W, Wt);
        flag_kernel  <<<(Q + 255) / 256, 256, 0, stream>>>(nid, flags, Q);
        hist_kernel  <<<2048, 256, 0, stream>>>(edst, flags, counts, E);
        alloc_kernel <<<(N + 255) / 256, 256, 0, stream>>>(counts, basep, pos, total, N);
        bucket_kernel<<<2048, 256, 0, stream>>>(esrc, edst, ew, flags, pos, bucket, E);

        int nb_acc = (int)(((size_t)N * 64 + 255) / 256);
        accum_nodes<<<nb_acc, 256, 0, stream>>>((const float4*)emb, bucket, basep,
                                                counts, flags, (float4*)agg, N);

        const int nb = (Q + TQ - 1) / TQ;
        gather_gemm<<<nb, 256, 0, stream>>>(agg, nid, Wt, b, out, Q);
    } else {
        hipMemsetAsync(agg, 0, (size_t)N * D * sizeof(float), stream);
        scatter_edges<<<2048, 256, 0, stream>>>((const float4*)emb, esrc, edst, ew, agg, E);
        const int nb = (Q + TQ - 1) / TQ;
        gather_gemm_w<<<nb, 256, 0, stream>>>(agg, nid, W, b, out, Q);
    }
}

// Round 5
// 405.712 us; speedup vs baseline: 1.4589x; 1.1218x over previous
//
#include <hip/hip_runtime.h>

#define D 256
#define TQ 32
#define GQ 64   // query rows per block in the MFMA GEMM

typedef __attribute__((ext_vector_type(8))) short short8;
typedef __attribute__((ext_vector_type(4))) float f32x4;

__device__ __forceinline__ unsigned short f2bf(float x) {
    unsigned int u = __float_as_uint(x);
    unsigned int r = (u + 0x7FFFu + ((u >> 16) & 1u)) >> 16;   // RNE
    return (unsigned short)r;
}

// ---------------- CSR-build path (no float atomics) ----------------

__global__ __launch_bounds__(256) void flag_kernel(
    const int* __restrict__ nid, unsigned char* __restrict__ flags, int Q)
{
    int q = blockIdx.x * 256 + threadIdx.x;
    if (q < Q) flags[nid[q]] = 1;
}

__global__ __launch_bounds__(256) void hist_kernel(
    const int* __restrict__ edst, const unsigned char* __restrict__ flags,
    int* __restrict__ counts, int E)
{
    int stride = gridDim.x * 256;
    for (int e = blockIdx.x * 256 + threadIdx.x; e < E; e += stride) {
        int d = edst[e];
        if (flags[d]) atomicAdd(&counts[d], 1);
    }
}

__global__ __launch_bounds__(256) void alloc_kernel(
    const int* __restrict__ counts, int* __restrict__ base,
    int* __restrict__ pos, int* __restrict__ total, int N)
{
    int n = blockIdx.x * 256 + threadIdx.x;
    if (n >= N) return;
    int c = counts[n];
    int b = 0;
    if (c > 0) b = atomicAdd(total, c);
    base[n] = b;
    pos[n]  = b;
}

__global__ __launch_bounds__(256) void bucket_kernel(
    const int* __restrict__ esrc, const int* __restrict__ edst,
    const float* __restrict__ ew, const unsigned char* __restrict__ flags,
    int* __restrict__ pos, int2* __restrict__ bucket, int E)
{
    int stride = gridDim.x * 256;
    for (int e = blockIdx.x * 256 + threadIdx.x; e < E; e += stride) {
        int d = edst[e];
        if (flags[d]) {
            int idx = atomicAdd(&pos[d], 1);
            bucket[idx] = make_int2(esrc[e], __float_as_int(ew[e]));
        }
    }
}

// One wave (64 lanes) per node: lane l owns float4 #l of the 256-float row.
__global__ __launch_bounds__(256) void accum_nodes(
    const float4* __restrict__ emb,      // [N][64] float4
    const int2*   __restrict__ bucket,   // packed {src, w}
    const int*    __restrict__ base,
    const int*    __restrict__ counts,
    const unsigned char* __restrict__ flags,
    float4*       __restrict__ agg,      // [N][64] float4
    int N)
{
    const int lane = threadIdx.x & 63;
    const int wid  = (int)((blockIdx.x * 256 + threadIdx.x) >> 6);
    if (wid >= N) return;
    if (!flags[wid]) return;

    const int b = base[wid];
    const int c = counts[wid];
    float4 acc = make_float4(0.f, 0.f, 0.f, 0.f);

    int i = 0;
    for (; i + 4 <= c; i += 4) {
        int2 s0 = bucket[b + i + 0];
        int2 s1 = bucket[b + i + 1];
        int2 s2 = bucket[b + i + 2];
        int2 s3 = bucket[b + i + 3];
        float4 v0 = emb[(size_t)s0.x * (D / 4) + lane];
        float4 v1 = emb[(size_t)s1.x * (D / 4) + lane];
        float4 v2 = emb[(size_t)s2.x * (D / 4) + lane];
        float4 v3 = emb[(size_t)s3.x * (D / 4) + lane];
        float w0 = __int_as_float(s0.y), w1 = __int_as_float(s1.y);
        float w2 = __int_as_float(s2.y), w3 = __int_as_float(s3.y);
        acc.x += v0.x * w0; acc.y += v0.y * w0; acc.z += v0.z * w0; acc.w += v0.w * w0;
        acc.x += v1.x * w1; acc.y += v1.y * w1; acc.z += v1.z * w1; acc.w += v1.w * w1;
        acc.x += v2.x * w2; acc.y += v2.y * w2; acc.z += v2.z * w2; acc.w += v2.w * w2;
        acc.x += v3.x * w3; acc.y += v3.y * w3; acc.z += v3.z * w3; acc.w += v3.w * w3;
    }
    for (; i < c; ++i) {
        int2 s = bucket[b + i];
        float4 v = emb[(size_t)s.x * (D / 4) + lane];
        float w = __int_as_float(s.y);
        acc.x += v.x * w; acc.y += v.y * w; acc.z += v.z * w; acc.w += v.w * w;
    }
    agg[(size_t)wid * (D / 4) + lane] = acc;
}

// ---------------- Fallback path (ws too small): atomics ----------------

__global__ __launch_bounds__(256) void scatter_edges(
    const float4* __restrict__ emb, const int* __restrict__ esrc,
    const int* __restrict__ edst, const float* __restrict__ ew,
    float* __restrict__ agg, int E)
{
    const int lane = threadIdx.x & 63;
    const int wid  = (int)((blockIdx.x * blockDim.x + threadIdx.x) >> 6);
    const int nw   = (int)((gridDim.x * blockDim.x) >> 6);
    for (int e = wid; e < E; e += nw) {
        const int   s = esrc[e];
        const int   d = edst[e];
        const float w = ew[e];
        float4 v = emb[(size_t)s * (D / 4) + lane];
        float* o = agg + (size_t)d * D + lane * 4;
        unsafeAtomicAdd(o + 0, v.x * w);
        unsafeAtomicAdd(o + 1, v.y * w);
        unsafeAtomicAdd(o + 2, v.z * w);
        unsafeAtomicAdd(o + 3, v.w * w);
    }
}

// ---------------- W convert: Wbf[j][k] = bf16(W[j][k]) (no transpose) --------
__global__ __launch_bounds__(256) void convert_w(
    const float* __restrict__ W, unsigned short* __restrict__ Wbf)
{
    int i = blockIdx.x * 256 + threadIdx.x;     // 8192 threads, 8 elems each
    const float4* src = (const float4*)W + (size_t)i * 2;
    float4 v0 = src[0];
    float4 v1 = src[1];
    short8 p;
    p[0] = (short)f2bf(v0.x); p[1] = (short)f2bf(v0.y);
    p[2] = (short)f2bf(v0.z); p[3] = (short)f2bf(v0.w);
    p[4] = (short)f2bf(v1.x); p[5] = (short)f2bf(v1.y);
    p[6] = (short)f2bf(v1.z); p[7] = (short)f2bf(v1.w);
    *((short8*)Wbf + i) = p;
}

// ---------------- Phase 2 (MFMA): out[q][j] = dot(feats[q], W[j]) + b[j] -----
// Block = 256 thr (4 waves), GQ=64 query rows. feats tile converted to bf16 in
// LDS [64][256] with XOR swizzle (byte ^= (row&7)<<4) -> conflict-free b128
// A-frag reads. A-frag: row=lane&15, k=(lane>>4)*8+e. B-frag from Wbf[j][k]:
// col j=lane&15, k contiguous -> 16B per lane, L1-resident. C/D: col=lane&15,
// row=(lane>>4)*4+reg (m89-verified).
__global__ __launch_bounds__(256) void gather_gemm_mfma(
    const float* __restrict__ agg, const int* __restrict__ nid,
    const unsigned short* __restrict__ Wbf,   // [256 j][256 k] bf16
    const float* __restrict__ b,
    float* __restrict__ out, int Q)
{
    __shared__ unsigned char lds[GQ * 512];   // 32 KB bf16 feats, swizzled
    const int t  = threadIdx.x;
    const int q0 = blockIdx.x * GQ;

    // Stage + convert: 64 rows x 32 chunks(16B bf16 each) = 2048; 8/thread.
    #pragma unroll
    for (int s = 0; s < 8; ++s) {
        const int i   = t + s * 256;
        const int row = i >> 5;
        const int ch  = i & 31;
        const int q   = q0 + row;
        float4 v0 = make_float4(0.f, 0.f, 0.f, 0.f), v1 = v0;
        if (q < Q) {
            const float4* src = (const float4*)agg + (size_t)nid[q] * 64 + ch * 2;
            v0 = src[0];
            v1 = src[1];
        }
        short8 p;
        p[0] = (short)f2bf(v0.x); p[1] = (short)f2bf(v0.y);
        p[2] = (short)f2bf(v0.z); p[3] = (short)f2bf(v0.w);
        p[4] = (short)f2bf(v1.x); p[5] = (short)f2bf(v1.y);
        p[6] = (short)f2bf(v1.z); p[7] = (short)f2bf(v1.w);
        int byte = row * 512 + ch * 16;
        byte ^= (row & 7) << 4;
        *(short8*)(lds + byte) = p;
    }
    __syncthreads();

    const int wave = t >> 6;
    const int lane = t & 63;
    const int qw   = wave * 16;          // wave's 16-row sub-tile
    const int lrow = lane & 15;
    const int kg   = lane >> 4;

    // Preload the wave's 8 A-fragments (32 VGPR).
    short8 afrag[8];
    #pragma unroll
    for (int ks = 0; ks < 8; ++ks) {
        int byte = (qw + lrow) * 512 + ks * 64 + kg * 16;
        byte ^= ((qw + lrow) & 7) << 4;
        afrag[ks] = *(const short8*)(lds + byte);
    }

    const unsigned short* wp0 = Wbf + (size_t)lrow * 256 + kg * 8;

    for (int jt = 0; jt < 16; ++jt) {
        f32x4 acc = {0.f, 0.f, 0.f, 0.f};
        const unsigned short* wp = wp0 + (size_t)jt * 16 * 256;
        #pragma unroll
        for (int ks = 0; ks < 8; ++ks) {
            short8 bfrag = *(const short8*)(wp + ks * 32);
            acc = __builtin_amdgcn_mfma_f32_16x16x32_bf16(afrag[ks], bfrag, acc, 0, 0, 0);
        }
        const float bias = b[jt * 16 + lrow];
        #pragma unroll
        for (int r = 0; r < 4; ++r) {
            const int row = kg * 4 + r;              // C row in 16x16 tile
            const int q   = q0 + qw + row;
            if (q < Q) out[(size_t)q * D + jt * 16 + lrow] = acc[r] + bias;
        }
    }
}

// Fallback GEMM reading W directly (f32), used only if ws can't hold Wbf.
__global__ __launch_bounds__(256) void gather_gemm_w(
    const float* __restrict__ agg, const int* __restrict__ nid,
    const float* __restrict__ W, const float* __restrict__ b,
    float* __restrict__ out, int Q)
{
    __shared__ float fl[TQ][D];
    const int t  = threadIdx.x;
    const int q0 = blockIdx.x * TQ;

    for (int i = t; i < TQ * (D / 4); i += 256) {
        const int r = i >> 6;
        const int c = i & 63;
        const int q = q0 + r;
        float4 v = make_float4(0.f, 0.f, 0.f, 0.f);
        if (q < Q) v = ((const float4*)agg)[(size_t)nid[q] * (D / 4) + c];
        ((float4*)&fl[r][0])[c] = v;
    }
    __syncthreads();

    const int j = t;
    float acc[TQ];
    #pragma unroll
    for (int r = 0; r < TQ; ++r) acc[r] = 0.f;

    const float4* wr4 = (const float4*)(W + (size_t)j * D);
    for (int k4 = 0; k4 < D / 4; ++k4) {
        const float4 w4 = wr4[k4];
        #pragma unroll
        for (int r = 0; r < TQ; ++r) {
            const float4 f = ((const float4*)&fl[r][0])[k4];
            acc[r] += f.x * w4.x + f.y * w4.y + f.z * w4.z + f.w * w4.w;
        }
    }

    const float bias = b[j];
    #pragma unroll
    for (int r = 0; r < TQ; ++r) {
        const int q = q0 + r;
        if (q < Q) out[(size_t)q * D + j] = acc[r] + bias;
    }
}

extern "C" void kernel_launch(void* const* d_in, const int* in_sizes, int n_in,
                              void* d_out, int out_size, void* d_ws, size_t ws_size,
                              hipStream_t stream) {
    const float* emb  = (const float*)d_in[0];
    const int*   esrc = (const int*)d_in[1];
    const int*   edst = (const int*)d_in[2];
    const float* ew   = (const float*)d_in[3];
    const int*   nid  = (const int*)d_in[4];
    const float* W    = (const float*)d_in[5];
    const float* b    = (const float*)d_in[6];
    float*       out  = (float*)d_out;

    const int N = in_sizes[0] / D;   // 100000
    const int E = in_sizes[1];       // 1600000
    const int Q = in_sizes[4];       // 50000

    char* wsb = (char*)d_ws;

    size_t off_agg    = 0;
    size_t off_counts = off_agg    + (size_t)N * D * sizeof(float);
    size_t off_base   = off_counts + (size_t)N * sizeof(int);
    size_t off_pos    = off_base   + (size_t)N * sizeof(int);
    size_t off_total  = off_pos    + (size_t)N * sizeof(int);
    size_t off_flags  = off_total  + 256;
    size_t off_bucket = off_flags  + (((size_t)N + 255) / 256) * 256;
    size_t off_wbf    = off_bucket + (size_t)E * sizeof(int2);
    size_t needed     = off_wbf    + (size_t)D * D * sizeof(unsigned short);

    float*          agg = (float*)(wsb + off_agg);
    unsigned short* Wbf = (unsigned short*)(wsb + off_wbf);

    const bool big_ws = (ws_size >= needed);

    if (big_ws) {
        int*           counts = (int*)(wsb + off_counts);
        int*           basep  = (int*)(wsb + off_base);
        int*           pos    = (int*)(wsb + off_pos);
        int*           total  = (int*)(wsb + off_total);
        unsigned char* flags  = (unsigned char*)(wsb + off_flags);
        int2*          bucket = (int2*)(wsb + off_bucket);

        hipMemsetAsync(wsb + off_counts, 0, off_bucket - off_counts, stream);

        convert_w    <<<32, 256, 0, stream>>>(W, Wbf);
        flag_kernel  <<<(Q + 255) / 256, 256, 0, stream>>>(nid, flags, Q);
        hist_kernel  <<<2048, 256, 0, stream>>>(edst, flags, counts, E);
        alloc_kernel <<<(N + 255) / 256, 256, 0, stream>>>(counts, basep, pos, total, N);
        bucket_kernel<<<2048, 256, 0, stream>>>(esrc, edst, ew, flags, pos, bucket, E);

        int nb_acc = (int)(((size_t)N * 64 + 255) / 256);
        accum_nodes<<<nb_acc, 256, 0, stream>>>((const float4*)emb, bucket, basep,
                                                counts, flags, (float4*)agg, N);

        const int nb = (Q + GQ - 1) / GQ;
        gather_gemm_mfma<<<nb, 256, 0, stream>>>(agg, nid, Wbf, b, out, Q);
    } else {
        hipMemsetAsync(agg, 0, (size_t)N * D * sizeof(float), stream);
        scatter_edges<<<2048, 256, 0, stream>>>((const float4*)emb, esrc, edst, ew, agg, E);
        const int nb = (Q + TQ - 1) / TQ;
        gather_gemm_w<<<nb, 256, 0, stream>>>(agg, nid, W, b, out, Q);
    }
}

// Round 9
// 402.781 us; speedup vs baseline: 1.4696x; 1.0073x over previous
//
#include <hip/hip_runtime.h>

#define D 256
#define TQ 32
#define GQ 64
#define NBW 3136   // bitmask words (padded): 100000 bits -> 3125, pad to 3136

typedef __attribute__((ext_vector_type(8))) short short8;
typedef __attribute__((ext_vector_type(4))) short short4v;
typedef __attribute__((ext_vector_type(4))) float f32x4;

__device__ __forceinline__ unsigned short f2bf(float x) {
    unsigned int u = __float_as_uint(x);
    unsigned int r = (u + 0x7FFFu + ((u >> 16) & 1u)) >> 16;   // RNE
    return (unsigned short)r;
}
__device__ __forceinline__ float bf2f(unsigned short h) {
    return __uint_as_float(((unsigned int)h) << 16);
}

// ---------------- converts ----------------

__global__ __launch_bounds__(256) void convert_emb(
    const float4* __restrict__ emb, short8* __restrict__ embbf, int total8)
{
    int stride = gridDim.x * 256;
    for (int i = blockIdx.x * 256 + threadIdx.x; i < total8; i += stride) {
        float4 v0 = emb[(size_t)i * 2 + 0];
        float4 v1 = emb[(size_t)i * 2 + 1];
        short8 p;
        p[0] = (short)f2bf(v0.x); p[1] = (short)f2bf(v0.y);
        p[2] = (short)f2bf(v0.z); p[3] = (short)f2bf(v0.w);
        p[4] = (short)f2bf(v1.x); p[5] = (short)f2bf(v1.y);
        p[6] = (short)f2bf(v1.z); p[7] = (short)f2bf(v1.w);
        embbf[i] = p;
    }
}

__global__ __launch_bounds__(256) void convert_w(
    const float* __restrict__ W, unsigned short* __restrict__ Wbf)
{
    int i = blockIdx.x * 256 + threadIdx.x;
    const float4* src = (const float4*)W + (size_t)i * 2;
    float4 v0 = src[0];
    float4 v1 = src[1];
    short8 p;
    p[0] = (short)f2bf(v0.x); p[1] = (short)f2bf(v0.y);
    p[2] = (short)f2bf(v0.z); p[3] = (short)f2bf(v0.w);
    p[4] = (short)f2bf(v1.x); p[5] = (short)f2bf(v1.y);
    p[6] = (short)f2bf(v1.z); p[7] = (short)f2bf(v1.w);
    *((short8*)Wbf + i) = p;
}

// ---------------- CSR build ----------------

__global__ __launch_bounds__(256) void flag_bits(
    const int* __restrict__ nid, unsigned int* __restrict__ bits, int Q)
{
    int q = blockIdx.x * 256 + threadIdx.x;
    if (q < Q) {
        int v = nid[q];
        atomicOr(&bits[v >> 5], 1u << (v & 31));
    }
}

__global__ __launch_bounds__(256) void hist_kernel(
    const int* __restrict__ edst, const unsigned int* __restrict__ bits,
    int* __restrict__ counts, int E)
{
    __shared__ unsigned int lb[NBW];
    for (int i = threadIdx.x; i < NBW; i += 256) lb[i] = bits[i];
    __syncthreads();
    int stride = gridDim.x * 256;
    for (int e = blockIdx.x * 256 + threadIdx.x; e < E; e += stride) {
        int d = edst[e];
        if ((lb[d >> 5] >> (d & 31)) & 1u) atomicAdd(&counts[d], 1);
    }
}

__global__ __launch_bounds__(256) void alloc_kernel(
    const int* __restrict__ counts, int* __restrict__ base,
    int* __restrict__ pos, int* __restrict__ total, int N)
{
    int n = blockIdx.x * 256 + threadIdx.x;
    if (n >= N) return;
    int c = counts[n];
    int b = 0;
    if (c > 0) b = atomicAdd(total, c);
    base[n] = b;
    pos[n]  = b;
}

__global__ __launch_bounds__(256) void bucket_kernel(
    const int* __restrict__ esrc, const int* __restrict__ edst,
    const float* __restrict__ ew, const unsigned int* __restrict__ bits,
    int* __restrict__ pos, int2* __restrict__ bucket, int E)
{
    __shared__ unsigned int lb[NBW];
    for (int i = threadIdx.x; i < NBW; i += 256) lb[i] = bits[i];
    __syncthreads();
    int stride = gridDim.x * 256;
    for (int e = blockIdx.x * 256 + threadIdx.x; e < E; e += stride) {
        int d = edst[e];
        if ((lb[d >> 5] >> (d & 31)) & 1u) {
            int idx = atomicAdd(&pos[d], 1);
            bucket[idx] = make_int2(esrc[e], __float_as_int(ew[e]));
        }
    }
}

// One wave per node; lane owns 4 bf16 elems (8B) of the 512B row.
__global__ __launch_bounds__(256) void accum_nodes(
    const short4v* __restrict__ embbf,   // [N][64] short4 (bf16)
    const int2*    __restrict__ bucket,
    const int*     __restrict__ base,
    const int*     __restrict__ counts,
    const unsigned int* __restrict__ bits,
    short4v*       __restrict__ aggbf,   // [N][64] short4 (bf16)
    int N)
{
    const int lane = threadIdx.x & 63;
    const int wid  = (int)((blockIdx.x * 256 + threadIdx.x) >> 6);
    if (wid >= N) return;
    if (!((bits[wid >> 5] >> (wid & 31)) & 1u)) return;

    const int b = base[wid];
    const int c = counts[wid];
    float a0 = 0.f, a1 = 0.f, a2 = 0.f, a3 = 0.f;

    int i = 0;
    for (; i + 8 <= c; i += 8) {
        #pragma unroll
        for (int u = 0; u < 8; ++u) {
            int2 s = bucket[b + i + u];
            short4v v = embbf[(size_t)s.x * 64 + lane];
            float w = __int_as_float(s.y);
            a0 += bf2f((unsigned short)v[0]) * w;
            a1 += bf2f((unsigned short)v[1]) * w;
            a2 += bf2f((unsigned short)v[2]) * w;
            a3 += bf2f((unsigned short)v[3]) * w;
        }
    }
    for (; i < c; ++i) {
        int2 s = bucket[b + i];
        short4v v = embbf[(size_t)s.x * 64 + lane];
        float w = __int_as_float(s.y);
        a0 += bf2f((unsigned short)v[0]) * w;
        a1 += bf2f((unsigned short)v[1]) * w;
        a2 += bf2f((unsigned short)v[2]) * w;
        a3 += bf2f((unsigned short)v[3]) * w;
    }
    short4v o;
    o[0] = (short)f2bf(a0); o[1] = (short)f2bf(a1);
    o[2] = (short)f2bf(a2); o[3] = (short)f2bf(a3);
    aggbf[(size_t)wid * 64 + lane] = o;
}

// ---------------- Phase 2 (MFMA) ----------------
__global__ __launch_bounds__(256) void gather_gemm_mfma(
    const unsigned short* __restrict__ aggbf,  // [N][256] bf16
    const int* __restrict__ nid,
    const unsigned short* __restrict__ Wbf,    // [256 j][256 k] bf16
    const float* __restrict__ b,
    float* __restrict__ out, int Q)
{
    __shared__ unsigned char lds[GQ * 512];
    const int t  = threadIdx.x;
    const int q0 = blockIdx.x * GQ;

    // Stage: 64 rows x 32 chunks (16B bf16) = 2048; 8 per thread. No convert.
    #pragma unroll
    for (int s = 0; s < 8; ++s) {
        const int i   = t + s * 256;
        const int row = i >> 5;
        const int ch  = i & 31;
        const int q   = q0 + row;
        short8 p = {0, 0, 0, 0, 0, 0, 0, 0};
        if (q < Q) p = *((const short8*)aggbf + (size_t)nid[q] * 32 + ch);
        int byte = row * 512 + ch * 16;
        byte ^= (row & 7) << 4;
        *(short8*)(lds + byte) = p;
    }
    __syncthreads();

    const int wave = t >> 6;
    const int lane = t & 63;
    const int qw   = wave * 16;
    const int lrow = lane & 15;
    const int kg   = lane >> 4;

    short8 afrag[8];
    #pragma unroll
    for (int ks = 0; ks < 8; ++ks) {
        int byte = (qw + lrow) * 512 + ks * 64 + kg * 16;
        byte ^= ((qw + lrow) & 7) << 4;
        afrag[ks] = *(const short8*)(lds + byte);
    }

    const unsigned short* wp0 = Wbf + (size_t)lrow * 256 + kg * 8;

    for (int jt = 0; jt < 16; ++jt) {
        f32x4 acc = {0.f, 0.f, 0.f, 0.f};
        const unsigned short* wp = wp0 + (size_t)jt * 16 * 256;
        #pragma unroll
        for (int ks = 0; ks < 8; ++ks) {
            short8 bfrag = *(const short8*)(wp + ks * 32);
            acc = __builtin_amdgcn_mfma_f32_16x16x32_bf16(afrag[ks], bfrag, acc, 0, 0, 0);
        }
        const float bias = b[jt * 16 + lrow];
        #pragma unroll
        for (int r = 0; r < 4; ++r) {
            const int row = kg * 4 + r;
            const int q   = q0 + qw + row;
            if (q < Q) out[(size_t)q * D + jt * 16 + lrow] = acc[r] + bias;
        }
    }
}

// ---------------- Fallback (small ws): f32 atomics + f32 GEMM ----------------

__global__ __launch_bounds__(256) void scatter_edges(
    const float4* __restrict__ emb, const int* __restrict__ esrc,
    const int* __restrict__ edst, const float* __restrict__ ew,
    float* __restrict__ agg, int E)
{
    const int lane = threadIdx.x & 63;
    const int wid  = (int)((blockIdx.x * blockDim.x + threadIdx.x) >> 6);
    const int nw   = (int)((gridDim.x * blockDim.x) >> 6);
    for (int e = wid; e < E; e += nw) {
        const int   s = esrc[e];
        const int   d = edst[e];
        const float w = ew[e];
        float4 v = emb[(size_t)s * (D / 4) + lane];
        float* o = agg + (size_t)d * D + lane * 4;
        unsafeAtomicAdd(o + 0, v.x * w);
        unsafeAtomicAdd(o + 1, v.y * w);
        unsafeAtomicAdd(o + 2, v.z * w);
        unsafeAtomicAdd(o + 3, v.w * w);
    }
}

__global__ __launch_bounds__(256) void gather_gemm_w(
    const float* __restrict__ agg, const int* __restrict__ nid,
    const float* __restrict__ W, const float* __restrict__ b,
    float* __restrict__ out, int Q)
{
    __shared__ float fl[TQ][D];
    const int t  = threadIdx.x;
    const int q0 = blockIdx.x * TQ;

    for (int i = t; i < TQ * (D / 4); i += 256) {
        const int r = i >> 6;
        const int c = i & 63;
        const int q = q0 + r;
        float4 v = make_float4(0.f, 0.f, 0.f, 0.f);
        if (q < Q) v = ((const float4*)agg)[(size_t)nid[q] * (D / 4) + c];
        ((float4*)&fl[r][0])[c] = v;
    }
    __syncthreads();

    const int j = t;
    float acc[TQ];
    #pragma unroll
    for (int r = 0; r < TQ; ++r) acc[r] = 0.f;

    const float4* wr4 = (const float4*)(W + (size_t)j * D);
    for (int k4 = 0; k4 < D / 4; ++k4) {
        const float4 w4 = wr4[k4];
        #pragma unroll
        for (int r = 0; r < TQ; ++r) {
            const float4 f = ((const float4*)&fl[r][0])[k4];
            acc[r] += f.x * w4.x + f.y * w4.y + f.z * w4.z + f.w * w4.w;
        }
    }

    const float bias = b[j];
    #pragma unroll
    for (int r = 0; r < TQ; ++r) {
        const int q = q0 + r;
        if (q < Q) out[(size_t)q * D + j] = acc[r] + bias;
    }
}

extern "C" void kernel_launch(void* const* d_in, const int* in_sizes, int n_in,
                              void* d_out, int out_size, void* d_ws, size_t ws_size,
                              hipStream_t stream) {
    const float* emb  = (const float*)d_in[0];
    const int*   esrc = (const int*)d_in[1];
    const int*   edst = (const int*)d_in[2];
    const float* ew   = (const float*)d_in[3];
    const int*   nid  = (const int*)d_in[4];
    const float* W    = (const float*)d_in[5];
    const float* b    = (const float*)d_in[6];
    float*       out  = (float*)d_out;

    const int N = in_sizes[0] / D;   // 100000
    const int E = in_sizes[1];       // 1600000
    const int Q = in_sizes[4];       // 50000

    char* wsb = (char*)d_ws;

    // bf16 layout (fits in the >=116.6 MB workspace proven available):
    size_t off_agg    = 0;                                         // bf16 agg
    size_t off_emb    = off_agg    + (size_t)N * D * 2;            // bf16 emb
    size_t off_counts = off_emb    + (size_t)N * D * 2;
    size_t off_base   = off_counts + (size_t)N * sizeof(int);
    size_t off_pos    = off_base   + (size_t)N * sizeof(int);
    size_t off_total  = off_pos    + (size_t)N * sizeof(int);
    size_t off_bits   = off_total  + 256;
    size_t off_bucket = off_bits   + (size_t)NBW * 4;
    size_t off_wbf    = off_bucket + (size_t)E * sizeof(int2);
    size_t needed     = off_wbf    + (size_t)D * D * 2;

    if (ws_size >= needed) {
        unsigned short* aggbf  = (unsigned short*)(wsb + off_agg);
        short8*         embbf  = (short8*)(wsb + off_emb);
        int*            counts = (int*)(wsb + off_counts);
        int*            basep  = (int*)(wsb + off_base);
        int*            pos    = (int*)(wsb + off_pos);
        int*            total  = (int*)(wsb + off_total);
        unsigned int*   bits   = (unsigned int*)(wsb + off_bits);
        int2*           bucket = (int2*)(wsb + off_bucket);
        unsigned short* Wbf    = (unsigned short*)(wsb + off_wbf);

        // Zero counts..bits (covers base/pos/total/bits) in one small memset.
        hipMemsetAsync(wsb + off_counts, 0, off_bucket - off_counts, stream);

        convert_emb  <<<2048, 256, 0, stream>>>((const float4*)emb, embbf, N * D / 8);
        convert_w    <<<32, 256, 0, stream>>>(W, Wbf);
        flag_bits    <<<(Q + 255) / 256, 256, 0, stream>>>(nid, bits, Q);
        hist_kernel  <<<2048, 256, 0, stream>>>(edst, bits, counts, E);
        alloc_kernel <<<(N + 255) / 256, 256, 0, stream>>>(counts, basep, pos, total, N);
        bucket_kernel<<<2048, 256, 0, stream>>>(esrc, edst, ew, bits, pos, bucket, E);

        int nb_acc = (int)(((size_t)N * 64 + 255) / 256);
        accum_nodes<<<nb_acc, 256, 0, stream>>>((const short4v*)embbf, bucket, basep,
                                                counts, bits, (short4v*)aggbf, N);

        const int nb = (Q + GQ - 1) / GQ;
        gather_gemm_mfma<<<nb, 256, 0, stream>>>(aggbf, nid, Wbf, b, out, Q);
    } else {
        float* agg = (float*)wsb;
        hipMemsetAsync(agg, 0, (size_t)N * D * sizeof(float), stream);
        scatter_edges<<<2048, 256, 0, stream>>>((const float4*)emb, esrc, edst, ew, agg, E);
        const int nb = (Q + TQ - 1) / TQ;
        gather_gemm_w<<<nb, 256, 0, stream>>>(agg, nid, W, b, out, Q);
    }
}